// Round 4
// baseline (801.369 us; speedup 1.0000x reference)
//
#include <hip/hip_runtime.h>

#define B_ 2048
#define T_ 256
#define F_ 128
#define H_ 64

typedef __attribute__((ext_vector_type(8))) short short8;   // 8 bf16
typedef __attribute__((ext_vector_type(4))) float f32x4;

// pack two floats to adjacent bf16 (RNE): low16 = a, high16 = b
__device__ __forceinline__ unsigned int rne2(float fa, float fb) {
    unsigned int ua = __float_as_uint(fa);
    unsigned int ub = __float_as_uint(fb);
    ua = ua + 0x7fffu + ((ua >> 16) & 1u);
    ub = ub + 0x7fffu + ((ub >> 16) & 1u);
    return (ua >> 16) | (ub & 0xffff0000u);
}
__device__ __forceinline__ float sigmoid_f(float v) {
    return __fdividef(1.0f, 1.0f + __expf(-v));
}
__device__ __forceinline__ float tanh_f(float v) {
    return 1.0f - __fdividef(2.0f, 1.0f + __expf(2.0f * v));  // overflow -> +/-1 correct
}
__device__ __forceinline__ float b2f(short v) {
    return __uint_as_float(((unsigned int)(unsigned short)v) << 16);
}

// Wave-per-row GRU, A-row-bit2-invariant edition.
// 256 threads = 4 waves; each WAVE owns ONE batch row, all 64 dims, all gates.
// Grid 512 blocks -> 2048 waves, exactly 2 resident waves/SIMD (2 blocks/CU).
//
// gx: 8 timesteps per burst, A-row m carries timestep tau(m)=(m&3)+4*(m>>3)
//   (bit 2 of m is pure replication via identical load addresses). 48 MFMA
//   per 8 steps. Gate at step tau reads C row (tau&3)+8*(tau>>2) on lanes
//   lq == 2*(tau>>2), reg tau&3.  (C layout row=lq*4+reg is R1-pinned.)
// gh: h_hi/h_lo live in LDS rows {8g, 8g+1} (g = tau>>2 alternates 0/1).
//   A-frag read uses row index (c & ~4) so A rows r and r^4 see identical
//   data -> result is invariant to the unpinned A-row bit 2.
//   12 N-tiles x 2 K-halves = 24 mfma/step, w_hh B-frags in 96 VGPRs.
// Ordering: compiler memory fence + __syncthreads() per step (insurance;
//   blocks are independent so cross-block latency hiding is unaffected).
__global__ __launch_bounds__(256, 2) void gru_fused(
    const float* __restrict__ x, const float* __restrict__ w_ih,
    const float* __restrict__ w_hh, const float* __restrict__ b_ih,
    const float* __restrict__ b_hh, const float* __restrict__ fc_w,
    const float* __restrict__ fc_b, float* __restrict__ out)
{
    __shared__ __align__(16) short wihf[12 * 4 * 64 * 8];   // 48 KB w_ih B-frags (bf16)
    __shared__ __align__(16) short ha[4][16][72];           // per-wave h rows (pad 72)
    __shared__ float bias_l[12][16];                        // gx bias per (tile, c)

    const int tid = threadIdx.x;
    const int wv  = tid >> 6;          // 0..3 (wave = batch row)
    const int l   = tid & 63;
    const int c   = l & 15;            // column within tile
    const int lq  = l >> 4;            // lane group 0..3
    const int row = blockIdx.x * 4 + wv;

    // ---- stage w_ih B-frags: slot s=(tile*4+ks)*64+L, el e = w_ih[tile*16+(L&15)][ks*32+(L>>4)*8+e]
    for (int s = tid; s < 12 * 4 * 64; s += 256) {
        const int n = s >> 8, ks = (s >> 6) & 3, L = s & 63;
        const float* wp = w_ih + (n * 16 + (L & 15)) * F_ + ks * 32 + ((L >> 4) * 8);
        const float4 a = *(const float4*)wp;
        const float4 b = *(const float4*)(wp + 4);
        union { short8 v; unsigned int u[4]; } fr;
        fr.u[0] = rne2(a.x, a.y); fr.u[1] = rne2(a.z, a.w);
        fr.u[2] = rne2(b.x, b.y); fr.u[3] = rne2(b.z, b.w);
        *(short8*)&wihf[s * 8] = fr.v;
    }
    // ---- zero h rows (h0 = 0; unused rows stay zero forever)
    for (int i = tid; i < 4 * 16 * 72; i += 256) ((short*)ha)[i] = 0;
    // ---- stage gx bias table: b_ih (+ b_hh for r,z tiles)
    if (tid < 192) {
        const int t = tid >> 4, cc = tid & 15;
        const int d = t * 16 + cc;
        bias_l[t][cc] = b_ih[d] + (t < 8 ? b_hh[d] : 0.0f);
    }

    // ---- per-lane n-gate recurrent bias
    float bnh[4];
    #pragma unroll
    for (int i = 0; i < 4; ++i) bnh[i] = b_hh[128 + i * 16 + c];

    // ---- w_hh B-frags -> registers (loop-invariant): whf[t][k2]
    // el e = w_hh[t*16 + c][k2*32 + lq*8 + e]
    short8 whf[12][2];
    #pragma unroll
    for (int t = 0; t < 12; ++t) {
        #pragma unroll
        for (int k2 = 0; k2 < 2; ++k2) {
            const float* wp = w_hh + (t * 16 + c) * H_ + k2 * 32 + lq * 8;
            const float4 a = *(const float4*)wp;
            const float4 b = *(const float4*)(wp + 4);
            union { short8 v; unsigned int u[4]; } fr;
            fr.u[0] = rne2(a.x, a.y); fr.u[1] = rne2(a.z, a.w);
            fr.u[2] = rne2(b.x, b.y); fr.u[3] = rne2(b.z, b.w);
            whf[t][k2] = fr.v;
        }
    }

    // A-side x mapping: lane carries timestep tau(c) = (c&3) + 4*(c>>3)
    // (bit 2 of c is replication: lanes c and c^4 load identical addresses)
    const int tau_c = (c & 3) | ((c >> 3) << 2);
    const float* xlane = x + ((size_t)row * T_ + tau_c) * F_ + lq * 8;
    short* hap = &ha[wv][0][0];
    const int ha_rd = (c & 11) * 72 + lq * 8;   // bit2-masked A-frag read base

    __syncthreads();   // wihf + zeroed ha + bias_l visible

    // ---- x staging: Xh reused; load ks01 -> cvt -> load ks23 -> cvt
    float4 Xh[4];
    short8 af[4];
    auto loadx = [&](const float* lp, int ksb) {
        #pragma unroll
        for (int k2 = 0; k2 < 2; ++k2) {
            Xh[2 * k2]     = *(const float4*)(lp + (ksb + k2) * 32);
            Xh[2 * k2 + 1] = *(const float4*)(lp + (ksb + k2) * 32 + 4);
        }
    };
    auto cvt2 = [&](int ksb) {
        #pragma unroll
        for (int k2 = 0; k2 < 2; ++k2) {
            union { short8 v; unsigned int u[4]; } fr;
            fr.u[0] = rne2(Xh[2 * k2].x,     Xh[2 * k2].y);
            fr.u[1] = rne2(Xh[2 * k2].z,     Xh[2 * k2].w);
            fr.u[2] = rne2(Xh[2 * k2 + 1].x, Xh[2 * k2 + 1].y);
            fr.u[3] = rne2(Xh[2 * k2 + 1].z, Xh[2 * k2 + 1].w);
            af[ksb + k2] = fr.v;
        }
    };
    loadx(xlane, 0); cvt2(0); loadx(xlane, 2); cvt2(2);

    f32x4 GXA[12];
    const f32x4 zc = {0.f, 0.f, 0.f, 0.f};
    auto burst = [&]() {   // gx for 8 steps: C row m -> step 8*macro + tau(m)
        #pragma unroll
        for (int t = 0; t < 12; ++t) {
            const float bv = bias_l[t][c];
            GXA[t] = (f32x4){bv, bv, bv, bv};
        }
        #pragma unroll
        for (int ks = 0; ks < 4; ++ks) {
            #pragma unroll
            for (int t = 0; t < 12; ++t)
                GXA[t] = __builtin_amdgcn_mfma_f32_16x16x32_bf16(
                    af[ks], *(const short8*)&wihf[(t * 4 + ks) * 512 + l * 8], GXA[t], 0, 0, 0);
        }
    };
    burst();

    #pragma unroll 1
    for (int m = 0; m < 32; ++m) {
        #pragma unroll
        for (int t2 = 0; t2 < 2; ++t2) {          // tau group: h rows 8*t2, 8*t2+1
            #pragma unroll
            for (int si = 0; si < 4; ++si) {
                const int tau = t2 * 4 + si;
                const int g2  = ((tau + 1) & 7) >> 2;   // next step's row group
                // ---- h A-frags (rows 8*t2, 8*t2+1 fresh; bit2-masked read)
                const short8 hA0 = *(const short8*)&hap[ha_rd];
                const short8 hA1 = *(const short8*)&hap[ha_rd + 32];
                // ---- h_prev for gate lanes (hi+lo from the fresh rows)
                float hp[4];
                #pragma unroll
                for (int i = 0; i < 4; ++i)
                    hp[i] = b2f(hap[(8 * t2) * 72 + i * 16 + c]) +
                            b2f(hap[(8 * t2 + 1) * 72 + i * 16 + c]);
                // ---- 24 MFMA: gh for all 12 tiles
                f32x4 GH[12];
                #pragma unroll
                for (int t = 0; t < 12; ++t)
                    GH[t] = __builtin_amdgcn_mfma_f32_16x16x32_bf16(hA0, whf[t][0], zc, 0, 0, 0);
                #pragma unroll
                for (int t = 0; t < 12; ++t)
                    GH[t] = __builtin_amdgcn_mfma_f32_16x16x32_bf16(hA1, whf[t][1], GH[t], 0, 0, 0);
                // ---- x prefetch for next macro (staged through Xh)
                if (tau == 1 && m < 31)
                    loadx(xlane + (size_t)(8 * (m + 1)) * F_, 0);
                if (tau == 3 && m < 31) {
                    cvt2(0);
                    loadx(xlane + (size_t)(8 * (m + 1)) * F_, 2);
                }
                if (tau == 5 && m < 31)
                    cvt2(2);
                // ---- gates on lanes lq == 2*t2, C reg si
                if (lq == 2 * t2) {
                    #pragma unroll
                    for (int i = 0; i < 4; ++i) {
                        const float ghr = GH[i][0]     + GH[i][1];
                        const float ghz = GH[4 + i][0] + GH[4 + i][1];
                        const float ghn = GH[8 + i][0] + GH[8 + i][1];
                        const float r = sigmoid_f(GXA[i][si] + ghr);
                        const float z = sigmoid_f(GXA[4 + i][si] + ghz);
                        const float n = tanh_f(GXA[8 + i][si] + r * (ghn + bnh[i]));
                        const float hn = n + z * (hp[i] - n);
                        const unsigned int uh = __float_as_uint(hn);
                        const unsigned int rr = uh + 0x7fffu + ((uh >> 16) & 1u);
                        const float hif = __uint_as_float(rr & 0xffff0000u);
                        const float lof = hn - hif;
                        const unsigned int ul = __float_as_uint(lof);
                        const unsigned int r2 = ul + 0x7fffu + ((ul >> 16) & 1u);
                        hap[(8 * g2)     * 72 + i * 16 + c] = (short)(rr >> 16);
                        hap[(8 * g2 + 1) * 72 + i * 16 + c] = (short)(r2 >> 16);
                    }
                }
                asm volatile("" ::: "memory");   // compiler fence: no ds reorder
                __syncthreads();                 // ordering insurance (per step)
            }
        }
        if (m < 31) burst();   // gx for next 8-step macro
    }

    // ===== epilogue: final h (after step 255) is in rows 0,1 =====
    {
        const float hv = b2f(hap[l]) + b2f(hap[72 + l]);
        float partial = hv * fc_w[l];
        #pragma unroll
        for (int msk = 1; msk <= 32; msk <<= 1) partial += __shfl_xor(partial, msk, 64);
        if (l == 0) out[row] = partial + fc_b[0];
    }
}

extern "C" void kernel_launch(void* const* d_in, const int* in_sizes, int n_in,
                              void* d_out, int out_size, void* d_ws, size_t ws_size,
                              hipStream_t stream)
{
    (void)in_sizes; (void)n_in; (void)out_size; (void)d_ws; (void)ws_size;
    const float* x    = (const float*)d_in[0];
    const float* w_ih = (const float*)d_in[1];
    const float* w_hh = (const float*)d_in[2];
    const float* b_ih = (const float*)d_in[3];
    const float* b_hh = (const float*)d_in[4];
    const float* fc_w = (const float*)d_in[5];
    const float* fc_b = (const float*)d_in[6];
    float* out = (float*)d_out;

    gru_fused<<<dim3(B_ / 4), 256, 0, stream>>>(
        x, w_ih, w_hh, b_ih, b_hh, fc_w, fc_b, out);
}